// Round 1
// baseline (839.011 us; speedup 1.0000x reference)
//
#include <hip/hip_runtime.h>
#include <cstdint>
#include <cstddef>

#define TPB 256
#define MAXT 128   // max targets stageable in LDS (T=64 in this problem)

// ---------------------------------------------------------------------------
// Kernel 1: anchor->target matching + smooth-L1 for positives + npos count.
// grid = (ceil(A/TPB), B), block = TPB.
// ---------------------------------------------------------------------------
__global__ void match_kernel(const float* __restrict__ bbox_preds,  // [B,A,4]
                             const float* __restrict__ bbox_tgts,   // [B,T,4] tlbr
                             const int*   __restrict__ clas_tgts,   // [B,T]
                             const float* __restrict__ anchors,     // [A,4] cthw
                             int A, int T,
                             int*    __restrict__ npos,     // [B]
                             float*  __restrict__ bb_sum,   // [B]
                             int8_t* __restrict__ codes)    // [B*A]
{
    const int b = blockIdx.y;
    const int a = blockIdx.x * blockDim.x + threadIdx.x;

    __shared__ float t_tl0[MAXT], t_tl1[MAXT], t_br0[MAXT], t_br1[MAXT];
    __shared__ float t_area[MAXT];
    __shared__ float t_c0[MAXT], t_c1[MAXT], t_s0[MAXT], t_s1[MAXT];
    __shared__ int   t_cls[MAXT];

    for (int i = threadIdx.x; i < T; i += blockDim.x) {
        const float y1 = bbox_tgts[((size_t)b * T + i) * 4 + 0];
        const float x1 = bbox_tgts[((size_t)b * T + i) * 4 + 1];
        const float y2 = bbox_tgts[((size_t)b * T + i) * 4 + 2];
        const float x2 = bbox_tgts[((size_t)b * T + i) * 4 + 3];
        // tlbr -> cthw (as reference does), then cthw -> tlbr for IoU
        const float c0 = (y1 + y2) * 0.5f, c1 = (x1 + x2) * 0.5f;
        const float s0 = y2 - y1,          s1 = x2 - x1;
        t_c0[i] = c0; t_c1[i] = c1; t_s0[i] = s0; t_s1[i] = s1;
        t_tl0[i] = c0 - s0 * 0.5f; t_tl1[i] = c1 - s1 * 0.5f;
        t_br0[i] = c0 + s0 * 0.5f; t_br1[i] = c1 + s1 * 0.5f;
        t_area[i] = s0 * s1;
        t_cls[i]  = clas_tgts[(size_t)b * T + i];
    }
    __syncthreads();

    const bool in = (a < A);
    float best = -1e30f;
    int   besti = 0;
    float4 anc = make_float4(0.f, 0.f, 1.f, 1.f);

    if (in) {
        anc = reinterpret_cast<const float4*>(anchors)[a];
        const float a_tl0 = anc.x - anc.z * 0.5f;
        const float a_tl1 = anc.y - anc.w * 0.5f;
        const float a_br0 = anc.x + anc.z * 0.5f;
        const float a_br1 = anc.y + anc.w * 0.5f;
        const float a_area = anc.z * anc.w;
        for (int t = 0; t < T; ++t) {
            float iou;
            if (t_cls[t] > 0) {
                const float tl0 = fmaxf(a_tl0, t_tl0[t]);
                const float tl1 = fmaxf(a_tl1, t_tl1[t]);
                const float br0 = fminf(a_br0, t_br0[t]);
                const float br1 = fminf(a_br1, t_br1[t]);
                const float sz0 = fmaxf(br0 - tl0, 0.0f);
                const float sz1 = fmaxf(br1 - tl1, 0.0f);
                const float inter = sz0 * sz1;
                const float uni = a_area + t_area[t] - inter;
                iou = inter / (uni + 1e-8f);
            } else {
                iou = -1.0f;
            }
            if (iou > best) { best = iou; besti = t; }  // strict > == first argmax
        }
    }

    const bool pos = in && (best > 0.5f);
    if (in) {
        int8_t code;
        if (pos)                 code = (int8_t)t_cls[besti];  // 1..C
        else if (best < 0.4f)    code = 0;                     // background
        else                     code = -1;                    // ignore
        codes[(size_t)b * A + a] = code;
    }

    float sl1 = 0.f;
    if (pos) {
        const float4 bp = reinterpret_cast<const float4*>(bbox_preds)[(size_t)b * A + a];
        const float tc0 = (t_c0[besti] - anc.x) / anc.z;
        const float tc1 = (t_c1[besti] - anc.y) / anc.w;
        const float ts0 = logf(t_s0[besti] / anc.z + 1e-8f);
        const float ts1 = logf(t_s1[besti] / anc.w + 1e-8f);
        const float r0 = tc0 / 0.1f, r1 = tc1 / 0.1f;
        const float r2 = ts0 / 0.2f, r3 = ts1 / 0.2f;
        const float d0 = bp.x - r0, d1 = bp.y - r1, d2 = bp.z - r2, d3 = bp.w - r3;
        const float a0 = fabsf(d0), a1 = fabsf(d1), a2 = fabsf(d2), a3 = fabsf(d3);
        sl1 += (a0 < 1.f) ? 0.5f * d0 * d0 : a0 - 0.5f;
        sl1 += (a1 < 1.f) ? 0.5f * d1 * d1 : a1 - 0.5f;
        sl1 += (a2 < 1.f) ? 0.5f * d2 * d2 : a2 - 0.5f;
        sl1 += (a3 < 1.f) ? 0.5f * d3 * d3 : a3 - 0.5f;
    }

    // block reduction: all threads still active (no early returns)
    float v = sl1;
    #pragma unroll
    for (int off = 32; off; off >>= 1) v += __shfl_down(v, off);
    const unsigned long long bal = __ballot(pos);

    __shared__ float s_sl1[TPB / 64];
    __shared__ int   s_np[TPB / 64];
    const int wid = threadIdx.x >> 6;
    if ((threadIdx.x & 63) == 0) { s_sl1[wid] = v; s_np[wid] = __popcll(bal); }
    __syncthreads();
    if (threadIdx.x == 0) {
        float tv = 0.f; int tn = 0;
        #pragma unroll
        for (int w = 0; w < TPB / 64; ++w) { tv += s_sl1[w]; tn += s_np[w]; }
        if (tv != 0.f) atomicAdd(&bb_sum[b], tv);
        if (tn != 0)   atomicAdd(&npos[b], tn);
    }
}

// ---------------------------------------------------------------------------
// Kernel 2: focal loss over [B, A, C], float4 along C.
// grid = (ceil(A*C/4 / TPB), B), block = TPB.
// ---------------------------------------------------------------------------
__global__ void focal_kernel(const float*  __restrict__ clas_preds,  // [B,A,C]
                             const int8_t* __restrict__ codes,       // [B*A]
                             int A, int C4,
                             float* __restrict__ clas_sum)           // [B]
{
    const int b = blockIdx.y;
    const long long e   = (long long)blockIdx.x * blockDim.x + threadIdx.x;
    const long long tot = (long long)A * C4;

    float local = 0.f;
    if (e < tot) {
        const int a  = (int)(e / C4);
        const int c4 = (int)(e % C4);
        const int code = codes[(size_t)b * A + a];
        if (code >= 0) {  // not ignored
            const float4 x4 =
                reinterpret_cast<const float4*>(clas_preds)[((size_t)b * A + a) * C4 + c4];
            const int target = code - 1;  // -1 => background (no one-hot match)
            const float xs[4] = {x4.x, x4.y, x4.z, x4.w};
            #pragma unroll
            for (int j = 0; j < 4; ++j) {
                const float x  = xs[j];
                const float ax = fabsf(x);
                const float em = expf(-ax);
                const float l  = log1pf(em);             // softplus(-|x|)
                const float sp_p = (x >= 0.f) ? (x + l) : l;   // softplus(x)
                const float sp_n = (x >= 0.f) ? l : (l - x);   // softplus(-x)
                const float s  = 1.f / (1.f + em);       // sigmoid(|x|)
                const float p  = (x >= 0.f) ? s : (1.f - s);   // sigmoid(x)
                const float q  = 1.f - p;
                const bool enc = ((c4 * 4 + j) == target);
                local += enc ? (0.75f * q * q * sp_n)
                             : (0.25f * p * p * sp_p);
            }
        }
    }

    // block reduction
    float v = local;
    #pragma unroll
    for (int off = 32; off; off >>= 1) v += __shfl_down(v, off);
    __shared__ float s_w[TPB / 64];
    const int wid = threadIdx.x >> 6;
    if ((threadIdx.x & 63) == 0) s_w[wid] = v;
    __syncthreads();
    if (threadIdx.x == 0) {
        float tv = 0.f;
        #pragma unroll
        for (int w = 0; w < TPB / 64; ++w) tv += s_w[w];
        if (tv != 0.f) atomicAdd(&clas_sum[b], tv);
    }
}

// ---------------------------------------------------------------------------
// Kernel 3: combine per-image losses -> scalar.
// ---------------------------------------------------------------------------
__global__ void finalize_kernel(const int*   __restrict__ npos,
                                const float* __restrict__ bb_sum,
                                const float* __restrict__ clas_sum,
                                int Bn, float* __restrict__ out)
{
    const int tid = threadIdx.x;
    float v = 0.f;
    if (tid < Bn) {
        const float np = (float)npos[tid];
        const float bb = bb_sum[tid]   / fmaxf(4.f * np, 1.f);
        const float cl = clas_sum[tid] / fmaxf(np, 1.f);
        v = bb + cl;
    }
    #pragma unroll
    for (int off = 32; off; off >>= 1) v += __shfl_down(v, off);
    if (tid == 0) out[0] = v / (float)Bn;
}

// ---------------------------------------------------------------------------
extern "C" void kernel_launch(void* const* d_in, const int* in_sizes, int n_in,
                              void* d_out, int out_size, void* d_ws, size_t ws_size,
                              hipStream_t stream)
{
    const float* clas_preds = (const float*)d_in[0];
    const float* bbox_preds = (const float*)d_in[1];
    const float* bbox_tgts  = (const float*)d_in[2];
    const int*   clas_tgts  = (const int*)d_in[3];
    const float* anchors    = (const float*)d_in[4];

    const int A  = in_sizes[4] / 4;
    const int Bn = in_sizes[1] / (A * 4);
    const int T  = in_sizes[3] / Bn;
    const int C  = in_sizes[0] / (Bn * A);
    const int C4 = C / 4;

    // workspace layout: npos[B] | bb_sum[B] | clas_sum[B] | codes[B*A]
    int*    npos     = (int*)d_ws;
    float*  bb_sum   = (float*)((char*)d_ws + (size_t)Bn * sizeof(int));
    float*  clas_sum = (float*)((char*)d_ws + (size_t)Bn * (sizeof(int) + sizeof(float)));
    int8_t* codes    = (int8_t*)((char*)d_ws + (size_t)Bn * (sizeof(int) + 2 * sizeof(float)));

    hipMemsetAsync(d_ws, 0, (size_t)Bn * 12, stream);

    dim3 g1((unsigned)((A + TPB - 1) / TPB), (unsigned)Bn);
    match_kernel<<<g1, TPB, 0, stream>>>(bbox_preds, bbox_tgts, clas_tgts, anchors,
                                         A, T, npos, bb_sum, codes);

    const long long tot = (long long)A * C4;
    dim3 g2((unsigned)((tot + TPB - 1) / TPB), (unsigned)Bn);
    focal_kernel<<<g2, TPB, 0, stream>>>(clas_preds, codes, A, C4, clas_sum);

    finalize_kernel<<<1, 64, 0, stream>>>(npos, bb_sum, clas_sum, Bn, (float*)d_out);
}

// Round 2
// 246.285 us; speedup vs baseline: 3.4067x; 3.4067x over previous
//
#include <hip/hip_runtime.h>
#include <cstdint>
#include <cstddef>

#define TPB 256
#define MAXT 128          // max targets stageable in LDS (T=64 here)
#define EPT 8             // elements (float4s) per thread in focal kernel

// ---------------------------------------------------------------------------
// Kernel 1: anchor->target matching + smooth-L1 for positives + npos count.
// grid = (ceil(A/TPB), B), block = TPB.
// Atomics here are rare (guarded by nonzero partials) -> cheap.
// ---------------------------------------------------------------------------
__global__ void match_kernel(const float* __restrict__ bbox_preds,  // [B,A,4]
                             const float* __restrict__ bbox_tgts,   // [B,T,4] tlbr
                             const int*   __restrict__ clas_tgts,   // [B,T]
                             const float* __restrict__ anchors,     // [A,4] cthw
                             int A, int T,
                             int*    __restrict__ npos,     // [B]
                             float*  __restrict__ bb_sum,   // [B]
                             int8_t* __restrict__ codes)    // [B*A]
{
    const int b = blockIdx.y;
    const int a = blockIdx.x * blockDim.x + threadIdx.x;

    __shared__ float t_tl0[MAXT], t_tl1[MAXT], t_br0[MAXT], t_br1[MAXT];
    __shared__ float t_area[MAXT];
    __shared__ float t_c0[MAXT], t_c1[MAXT], t_s0[MAXT], t_s1[MAXT];
    __shared__ int   t_cls[MAXT];

    for (int i = threadIdx.x; i < T; i += blockDim.x) {
        const float y1 = bbox_tgts[((size_t)b * T + i) * 4 + 0];
        const float x1 = bbox_tgts[((size_t)b * T + i) * 4 + 1];
        const float y2 = bbox_tgts[((size_t)b * T + i) * 4 + 2];
        const float x2 = bbox_tgts[((size_t)b * T + i) * 4 + 3];
        const float c0 = (y1 + y2) * 0.5f, c1 = (x1 + x2) * 0.5f;
        const float s0 = y2 - y1,          s1 = x2 - x1;
        t_c0[i] = c0; t_c1[i] = c1; t_s0[i] = s0; t_s1[i] = s1;
        t_tl0[i] = c0 - s0 * 0.5f; t_tl1[i] = c1 - s1 * 0.5f;
        t_br0[i] = c0 + s0 * 0.5f; t_br1[i] = c1 + s1 * 0.5f;
        t_area[i] = s0 * s1;
        t_cls[i]  = clas_tgts[(size_t)b * T + i];
    }
    __syncthreads();

    const bool in = (a < A);
    float best = -1e30f;
    int   besti = 0;
    float4 anc = make_float4(0.f, 0.f, 1.f, 1.f);

    if (in) {
        anc = reinterpret_cast<const float4*>(anchors)[a];
        const float a_tl0 = anc.x - anc.z * 0.5f;
        const float a_tl1 = anc.y - anc.w * 0.5f;
        const float a_br0 = anc.x + anc.z * 0.5f;
        const float a_br1 = anc.y + anc.w * 0.5f;
        const float a_area = anc.z * anc.w;
        for (int t = 0; t < T; ++t) {
            float iou;
            if (t_cls[t] > 0) {
                const float tl0 = fmaxf(a_tl0, t_tl0[t]);
                const float tl1 = fmaxf(a_tl1, t_tl1[t]);
                const float br0 = fminf(a_br0, t_br0[t]);
                const float br1 = fminf(a_br1, t_br1[t]);
                const float sz0 = fmaxf(br0 - tl0, 0.0f);
                const float sz1 = fmaxf(br1 - tl1, 0.0f);
                const float inter = sz0 * sz1;
                const float uni = a_area + t_area[t] - inter;
                iou = inter / (uni + 1e-8f);
            } else {
                iou = -1.0f;
            }
            if (iou > best) { best = iou; besti = t; }  // strict > == first argmax
        }
    }

    const bool pos = in && (best > 0.5f);
    if (in) {
        int8_t code;
        if (pos)                 code = (int8_t)t_cls[besti];  // 1..C
        else if (best < 0.4f)    code = 0;                     // background
        else                     code = -1;                    // ignore
        codes[(size_t)b * A + a] = code;
    }

    float sl1 = 0.f;
    if (pos) {
        const float4 bp = reinterpret_cast<const float4*>(bbox_preds)[(size_t)b * A + a];
        const float tc0 = (t_c0[besti] - anc.x) / anc.z;
        const float tc1 = (t_c1[besti] - anc.y) / anc.w;
        const float ts0 = logf(t_s0[besti] / anc.z + 1e-8f);
        const float ts1 = logf(t_s1[besti] / anc.w + 1e-8f);
        const float r0 = tc0 / 0.1f, r1 = tc1 / 0.1f;
        const float r2 = ts0 / 0.2f, r3 = ts1 / 0.2f;
        const float d0 = bp.x - r0, d1 = bp.y - r1, d2 = bp.z - r2, d3 = bp.w - r3;
        const float a0 = fabsf(d0), a1 = fabsf(d1), a2 = fabsf(d2), a3 = fabsf(d3);
        sl1 += (a0 < 1.f) ? 0.5f * d0 * d0 : a0 - 0.5f;
        sl1 += (a1 < 1.f) ? 0.5f * d1 * d1 : a1 - 0.5f;
        sl1 += (a2 < 1.f) ? 0.5f * d2 * d2 : a2 - 0.5f;
        sl1 += (a3 < 1.f) ? 0.5f * d3 * d3 : a3 - 0.5f;
    }

    float v = sl1;
    #pragma unroll
    for (int off = 32; off; off >>= 1) v += __shfl_down(v, off);
    const unsigned long long bal = __ballot(pos);

    __shared__ float s_sl1[TPB / 64];
    __shared__ int   s_np[TPB / 64];
    const int wid = threadIdx.x >> 6;
    if ((threadIdx.x & 63) == 0) { s_sl1[wid] = v; s_np[wid] = __popcll(bal); }
    __syncthreads();
    if (threadIdx.x == 0) {
        float tv = 0.f; int tn = 0;
        #pragma unroll
        for (int w = 0; w < TPB / 64; ++w) { tv += s_sl1[w]; tn += s_np[w]; }
        if (tv != 0.f) atomicAdd(&bb_sum[b], tv);
        if (tn != 0)   atomicAdd(&npos[b], tn);
    }
}

// ---------------------------------------------------------------------------
// Kernel 2: focal loss over [B, A, C], float4 along C, EPT float4s per thread.
// grid = (ceil(A*C4 / (TPB*EPT)), B).  NO atomics: per-block partial -> ws.
// ---------------------------------------------------------------------------
__global__ void focal_kernel(const float*  __restrict__ clas_preds,  // [B,A,C]
                             const int8_t* __restrict__ codes,       // [B*A]
                             int A, int C4,
                             float* __restrict__ partials)           // [B*gridDim.x]
{
    const int b = blockIdx.y;
    const unsigned tot  = (unsigned)A * (unsigned)C4;
    const unsigned base = blockIdx.x * (TPB * EPT) + threadIdx.x;
    const size_t img_off = (size_t)b * A;

    float local = 0.f;
    #pragma unroll
    for (int k = 0; k < EPT; ++k) {
        const unsigned e = base + (unsigned)k * TPB;
        if (e < tot) {
            const unsigned a  = e / (unsigned)C4;   // 32-bit div
            const unsigned c4 = e - a * (unsigned)C4;
            const int code = codes[img_off + a];
            if (code >= 0) {  // not ignored
                const float4 x4 =
                    reinterpret_cast<const float4*>(clas_preds)[(img_off + a) * C4 + c4];
                const int target = code - 1;  // -1 => background (no one-hot hit)
                const float xs[4] = {x4.x, x4.y, x4.z, x4.w};
                #pragma unroll
                for (int j = 0; j < 4; ++j) {
                    const float x  = xs[j];
                    const float ax = fabsf(x);
                    const float em = expf(-ax);
                    const float l  = log1pf(em);                   // softplus(-|x|)
                    const float sp_p = (x >= 0.f) ? (x + l) : l;   // softplus(x)
                    const float sp_n = (x >= 0.f) ? l : (l - x);   // softplus(-x)
                    const float s  = 1.f / (1.f + em);             // sigmoid(|x|)
                    const float p  = (x >= 0.f) ? s : (1.f - s);   // sigmoid(x)
                    const float q  = 1.f - p;
                    const bool enc = ((int)(c4 * 4 + j) == target);
                    local += enc ? (0.75f * q * q * sp_n)
                                 : (0.25f * p * p * sp_p);
                }
            }
        }
    }

    float v = local;
    #pragma unroll
    for (int off = 32; off; off >>= 1) v += __shfl_down(v, off);
    __shared__ float s_w[TPB / 64];
    const int wid = threadIdx.x >> 6;
    if ((threadIdx.x & 63) == 0) s_w[wid] = v;
    __syncthreads();
    if (threadIdx.x == 0) {
        float tv = 0.f;
        #pragma unroll
        for (int w = 0; w < TPB / 64; ++w) tv += s_w[w];
        partials[(size_t)b * gridDim.x + blockIdx.x] = tv;   // plain store, no atomic
    }
}

// ---------------------------------------------------------------------------
// Kernel 3: per-image reduce of focal partials + combine with bbox loss.
// grid = (B), block = TPB.
// ---------------------------------------------------------------------------
__global__ void img_reduce_kernel(const float* __restrict__ partials, // [B*nblk]
                                  int nblk,
                                  const int*   __restrict__ npos,
                                  const float* __restrict__ bb_sum,
                                  float* __restrict__ img_loss)       // [B]
{
    const int b = blockIdx.x;
    float v = 0.f;
    for (int i = threadIdx.x; i < nblk; i += blockDim.x)
        v += partials[(size_t)b * nblk + i];
    #pragma unroll
    for (int off = 32; off; off >>= 1) v += __shfl_down(v, off);
    __shared__ float s_w[TPB / 64];
    const int wid = threadIdx.x >> 6;
    if ((threadIdx.x & 63) == 0) s_w[wid] = v;
    __syncthreads();
    if (threadIdx.x == 0) {
        float cl = 0.f;
        #pragma unroll
        for (int w = 0; w < TPB / 64; ++w) cl += s_w[w];
        const float np = (float)npos[b];
        img_loss[b] = bb_sum[b] / fmaxf(4.f * np, 1.f) + cl / fmaxf(np, 1.f);
    }
}

// ---------------------------------------------------------------------------
// Kernel 4: sum per-image losses -> scalar / B.
// ---------------------------------------------------------------------------
__global__ void finalize_kernel(const float* __restrict__ img_loss,
                                int Bn, float* __restrict__ out)
{
    const int tid = threadIdx.x;
    float v = (tid < Bn) ? img_loss[tid] : 0.f;
    #pragma unroll
    for (int off = 32; off; off >>= 1) v += __shfl_down(v, off);
    if (tid == 0) out[0] = v / (float)Bn;
}

// ---------------------------------------------------------------------------
extern "C" void kernel_launch(void* const* d_in, const int* in_sizes, int n_in,
                              void* d_out, int out_size, void* d_ws, size_t ws_size,
                              hipStream_t stream)
{
    const float* clas_preds = (const float*)d_in[0];
    const float* bbox_preds = (const float*)d_in[1];
    const float* bbox_tgts  = (const float*)d_in[2];
    const int*   clas_tgts  = (const int*)d_in[3];
    const float* anchors    = (const float*)d_in[4];

    const int A  = in_sizes[4] / 4;
    const int Bn = in_sizes[1] / (A * 4);
    const int T  = in_sizes[3] / Bn;
    const int C  = in_sizes[0] / (Bn * A);
    const int C4 = C / 4;

    const unsigned tot   = (unsigned)A * (unsigned)C4;
    const unsigned nblk  = (tot + TPB * EPT - 1) / (TPB * EPT);

    // workspace layout (floats/ints first for alignment, bytes last):
    // npos[B] | bb_sum[B] | img_loss[B] | partials[B*nblk] | codes[B*A]
    char* ws = (char*)d_ws;
    int*    npos     = (int*)ws;                                   ws += (size_t)Bn * sizeof(int);
    float*  bb_sum   = (float*)ws;                                 ws += (size_t)Bn * sizeof(float);
    float*  img_loss = (float*)ws;                                 ws += (size_t)Bn * sizeof(float);
    float*  partials = (float*)ws;                                 ws += (size_t)Bn * nblk * sizeof(float);
    int8_t* codes    = (int8_t*)ws;

    // zero only npos + bb_sum (8B per image)
    hipMemsetAsync(d_ws, 0, (size_t)Bn * 8, stream);

    dim3 g1((unsigned)((A + TPB - 1) / TPB), (unsigned)Bn);
    match_kernel<<<g1, TPB, 0, stream>>>(bbox_preds, bbox_tgts, clas_tgts, anchors,
                                         A, T, npos, bb_sum, codes);

    dim3 g2(nblk, (unsigned)Bn);
    focal_kernel<<<g2, TPB, 0, stream>>>(clas_preds, codes, A, C4, partials);

    img_reduce_kernel<<<Bn, TPB, 0, stream>>>(partials, (int)nblk, npos, bb_sum, img_loss);

    finalize_kernel<<<1, 64, 0, stream>>>(img_loss, Bn, (float*)d_out);
}

// Round 3
// 105.584 us; speedup vs baseline: 7.9464x; 2.3326x over previous
//
#include <hip/hip_runtime.h>
#include <cstdint>
#include <cstddef>

#define TPB 256
#define MAXT 128          // max targets stageable in LDS (T=64 here)
#define EPT 8             // float4s per thread in focal kernel

// ---------------------------------------------------------------------------
// Kernel 1: anchor->target matching + smooth-L1 for positives + npos count.
// grid = (ceil(A/TPB), B), block = TPB.
// ---------------------------------------------------------------------------
__global__ void match_kernel(const float* __restrict__ bbox_preds,  // [B,A,4]
                             const float* __restrict__ bbox_tgts,   // [B,T,4] tlbr
                             const int*   __restrict__ clas_tgts,   // [B,T]
                             const float* __restrict__ anchors,     // [A,4] cthw
                             int A, int T,
                             int*    __restrict__ npos,     // [B]
                             float*  __restrict__ bb_sum,   // [B]
                             int8_t* __restrict__ codes)    // [B*A]
{
    const int b = blockIdx.y;
    const int a = blockIdx.x * blockDim.x + threadIdx.x;

    __shared__ float t_tl0[MAXT], t_tl1[MAXT], t_br0[MAXT], t_br1[MAXT];
    __shared__ float t_area[MAXT];
    __shared__ float t_c0[MAXT], t_c1[MAXT], t_s0[MAXT], t_s1[MAXT];
    __shared__ int   t_cls[MAXT];

    for (int i = threadIdx.x; i < T; i += blockDim.x) {
        const float y1 = bbox_tgts[((size_t)b * T + i) * 4 + 0];
        const float x1 = bbox_tgts[((size_t)b * T + i) * 4 + 1];
        const float y2 = bbox_tgts[((size_t)b * T + i) * 4 + 2];
        const float x2 = bbox_tgts[((size_t)b * T + i) * 4 + 3];
        const float c0 = (y1 + y2) * 0.5f, c1 = (x1 + x2) * 0.5f;
        const float s0 = y2 - y1,          s1 = x2 - x1;
        t_c0[i] = c0; t_c1[i] = c1; t_s0[i] = s0; t_s1[i] = s1;
        t_tl0[i] = c0 - s0 * 0.5f; t_tl1[i] = c1 - s1 * 0.5f;
        t_br0[i] = c0 + s0 * 0.5f; t_br1[i] = c1 + s1 * 0.5f;
        t_area[i] = s0 * s1;
        t_cls[i]  = clas_tgts[(size_t)b * T + i];
    }
    __syncthreads();

    const bool in = (a < A);
    float best = -1e30f;
    int   besti = 0;
    float4 anc = make_float4(0.f, 0.f, 1.f, 1.f);

    if (in) {
        anc = reinterpret_cast<const float4*>(anchors)[a];
        const float a_tl0 = anc.x - anc.z * 0.5f;
        const float a_tl1 = anc.y - anc.w * 0.5f;
        const float a_br0 = anc.x + anc.z * 0.5f;
        const float a_br1 = anc.y + anc.w * 0.5f;
        const float a_area = anc.z * anc.w;
        for (int t = 0; t < T; ++t) {
            float iou;
            if (t_cls[t] > 0) {
                const float tl0 = fmaxf(a_tl0, t_tl0[t]);
                const float tl1 = fmaxf(a_tl1, t_tl1[t]);
                const float br0 = fminf(a_br0, t_br0[t]);
                const float br1 = fminf(a_br1, t_br1[t]);
                const float sz0 = fmaxf(br0 - tl0, 0.0f);
                const float sz1 = fmaxf(br1 - tl1, 0.0f);
                const float inter = sz0 * sz1;
                const float uni = a_area + t_area[t] - inter;
                iou = inter / (uni + 1e-8f);
            } else {
                iou = -1.0f;
            }
            if (iou > best) { best = iou; besti = t; }  // strict > == first argmax
        }
    }

    const bool pos = in && (best > 0.5f);
    if (in) {
        int8_t code;
        if (pos)                 code = (int8_t)t_cls[besti];  // 1..C
        else if (best < 0.4f)    code = 0;                     // background
        else                     code = -1;                    // ignore
        codes[(size_t)b * A + a] = code;
    }

    float sl1 = 0.f;
    if (pos) {
        // precise logf here: only runs for ~npos anchors, cost negligible
        const float4 bp = reinterpret_cast<const float4*>(bbox_preds)[(size_t)b * A + a];
        const float tc0 = (t_c0[besti] - anc.x) / anc.z;
        const float tc1 = (t_c1[besti] - anc.y) / anc.w;
        const float ts0 = logf(t_s0[besti] / anc.z + 1e-8f);
        const float ts1 = logf(t_s1[besti] / anc.w + 1e-8f);
        const float r0 = tc0 / 0.1f, r1 = tc1 / 0.1f;
        const float r2 = ts0 / 0.2f, r3 = ts1 / 0.2f;
        const float d0 = bp.x - r0, d1 = bp.y - r1, d2 = bp.z - r2, d3 = bp.w - r3;
        const float a0 = fabsf(d0), a1 = fabsf(d1), a2 = fabsf(d2), a3 = fabsf(d3);
        sl1 += (a0 < 1.f) ? 0.5f * d0 * d0 : a0 - 0.5f;
        sl1 += (a1 < 1.f) ? 0.5f * d1 * d1 : a1 - 0.5f;
        sl1 += (a2 < 1.f) ? 0.5f * d2 * d2 : a2 - 0.5f;
        sl1 += (a3 < 1.f) ? 0.5f * d3 * d3 : a3 - 0.5f;
    }

    float v = sl1;
    #pragma unroll
    for (int off = 32; off; off >>= 1) v += __shfl_down(v, off);
    const unsigned long long bal = __ballot(pos);

    __shared__ float s_sl1[TPB / 64];
    __shared__ int   s_np[TPB / 64];
    const int wid = threadIdx.x >> 6;
    if ((threadIdx.x & 63) == 0) { s_sl1[wid] = v; s_np[wid] = __popcll(bal); }
    __syncthreads();
    if (threadIdx.x == 0) {
        float tv = 0.f; int tn = 0;
        #pragma unroll
        for (int w = 0; w < TPB / 64; ++w) { tv += s_sl1[w]; tn += s_np[w]; }
        if (tv != 0.f) atomicAdd(&bb_sum[b], tv);
        if (tn != 0)   atomicAdd(&npos[b], tn);
    }
}

// ---------------------------------------------------------------------------
// Kernel 2: focal loss over [B, A, C], float4 along C, EPT float4s per thread.
// Hardware transcendentals: v_exp_f32 / v_log_f32 / v_rcp_f32 (quarter-rate),
// ~15 VALU + 3 trans per element instead of libm expf/log1pf sequences.
// ---------------------------------------------------------------------------
__global__ void focal_kernel(const float*  __restrict__ clas_preds,  // [B,A,C]
                             const int8_t* __restrict__ codes,       // [B*A]
                             int A, int C4,
                             float* __restrict__ partials)           // [B*gridDim.x]
{
    const int b = blockIdx.y;
    const unsigned tot  = (unsigned)A * (unsigned)C4;
    const unsigned base = blockIdx.x * (TPB * EPT) + threadIdx.x;
    const size_t img_off = (size_t)b * A;

    float local = 0.f;
    #pragma unroll
    for (int k = 0; k < EPT; ++k) {
        const unsigned e = base + (unsigned)k * TPB;
        if (e < tot) {
            const unsigned a  = e / (unsigned)C4;   // 32-bit div
            const unsigned c4 = e - a * (unsigned)C4;
            const int code = codes[img_off + a];
            if (code >= 0) {  // not ignored
                const float4 x4 =
                    reinterpret_cast<const float4*>(clas_preds)[(img_off + a) * C4 + c4];
                const int target = code - 1;  // -1 => background (no one-hot hit)
                const float xs[4] = {x4.x, x4.y, x4.z, x4.w};
                #pragma unroll
                for (int j = 0; j < 4; ++j) {
                    const float x  = xs[j];
                    const float ax = fabsf(x);
                    // exp(-|x|) via hardware exp2
                    const float em = __builtin_amdgcn_exp2f(ax * -1.44269504089f);
                    const float one_em = 1.f + em;
                    // log1p(em) via hardware log2 (em in (0,1]: no cancellation risk)
                    const float l = __builtin_amdgcn_logf(one_em) * 0.69314718056f;
                    const float s = __builtin_amdgcn_rcpf(one_em);   // sigmoid(|x|)
                    const bool nonneg = (x >= 0.f);
                    const float sp_p = nonneg ? (x + l) : l;   // softplus(x)
                    const float sp_n = sp_p - x;               // softplus(-x)
                    const float p  = nonneg ? s : (1.f - s);   // sigmoid(x)
                    const float q  = 1.f - p;
                    const bool enc = ((int)(c4 * 4 + j) == target);
                    local += enc ? (0.75f * q * q * sp_n)
                                 : (0.25f * p * p * sp_p);
                }
            }
        }
    }

    float v = local;
    #pragma unroll
    for (int off = 32; off; off >>= 1) v += __shfl_down(v, off);
    __shared__ float s_w[TPB / 64];
    const int wid = threadIdx.x >> 6;
    if ((threadIdx.x & 63) == 0) s_w[wid] = v;
    __syncthreads();
    if (threadIdx.x == 0) {
        float tv = 0.f;
        #pragma unroll
        for (int w = 0; w < TPB / 64; ++w) tv += s_w[w];
        partials[(size_t)b * gridDim.x + blockIdx.x] = tv;   // plain store, no atomic
    }
}

// ---------------------------------------------------------------------------
// Kernel 3: per-image reduce of focal partials + combine with bbox loss.
// ---------------------------------------------------------------------------
__global__ void img_reduce_kernel(const float* __restrict__ partials, // [B*nblk]
                                  int nblk,
                                  const int*   __restrict__ npos,
                                  const float* __restrict__ bb_sum,
                                  float* __restrict__ img_loss)       // [B]
{
    const int b = blockIdx.x;
    float v = 0.f;
    for (int i = threadIdx.x; i < nblk; i += blockDim.x)
        v += partials[(size_t)b * nblk + i];
    #pragma unroll
    for (int off = 32; off; off >>= 1) v += __shfl_down(v, off);
    __shared__ float s_w[TPB / 64];
    const int wid = threadIdx.x >> 6;
    if ((threadIdx.x & 63) == 0) s_w[wid] = v;
    __syncthreads();
    if (threadIdx.x == 0) {
        float cl = 0.f;
        #pragma unroll
        for (int w = 0; w < TPB / 64; ++w) cl += s_w[w];
        const float np = (float)npos[b];
        img_loss[b] = bb_sum[b] / fmaxf(4.f * np, 1.f) + cl / fmaxf(np, 1.f);
    }
}

// ---------------------------------------------------------------------------
// Kernel 4: sum per-image losses -> scalar / B.
// ---------------------------------------------------------------------------
__global__ void finalize_kernel(const float* __restrict__ img_loss,
                                int Bn, float* __restrict__ out)
{
    const int tid = threadIdx.x;
    float v = (tid < Bn) ? img_loss[tid] : 0.f;
    #pragma unroll
    for (int off = 32; off; off >>= 1) v += __shfl_down(v, off);
    if (tid == 0) out[0] = v / (float)Bn;
}

// ---------------------------------------------------------------------------
extern "C" void kernel_launch(void* const* d_in, const int* in_sizes, int n_in,
                              void* d_out, int out_size, void* d_ws, size_t ws_size,
                              hipStream_t stream)
{
    const float* clas_preds = (const float*)d_in[0];
    const float* bbox_preds = (const float*)d_in[1];
    const float* bbox_tgts  = (const float*)d_in[2];
    const int*   clas_tgts  = (const int*)d_in[3];
    const float* anchors    = (const float*)d_in[4];

    const int A  = in_sizes[4] / 4;
    const int Bn = in_sizes[1] / (A * 4);
    const int T  = in_sizes[3] / Bn;
    const int C  = in_sizes[0] / (Bn * A);
    const int C4 = C / 4;

    const unsigned tot   = (unsigned)A * (unsigned)C4;
    const unsigned nblk  = (tot + TPB * EPT - 1) / (TPB * EPT);

    // workspace layout: npos[B] | bb_sum[B] | img_loss[B] | partials[B*nblk] | codes[B*A]
    char* ws = (char*)d_ws;
    int*    npos     = (int*)ws;    ws += (size_t)Bn * sizeof(int);
    float*  bb_sum   = (float*)ws;  ws += (size_t)Bn * sizeof(float);
    float*  img_loss = (float*)ws;  ws += (size_t)Bn * sizeof(float);
    float*  partials = (float*)ws;  ws += (size_t)Bn * nblk * sizeof(float);
    int8_t* codes    = (int8_t*)ws;

    hipMemsetAsync(d_ws, 0, (size_t)Bn * 8, stream);  // zero npos + bb_sum

    dim3 g1((unsigned)((A + TPB - 1) / TPB), (unsigned)Bn);
    match_kernel<<<g1, TPB, 0, stream>>>(bbox_preds, bbox_tgts, clas_tgts, anchors,
                                         A, T, npos, bb_sum, codes);

    dim3 g2(nblk, (unsigned)Bn);
    focal_kernel<<<g2, TPB, 0, stream>>>(clas_preds, codes, A, C4, partials);

    img_reduce_kernel<<<Bn, TPB, 0, stream>>>(partials, (int)nblk, npos, bb_sum, img_loss);

    finalize_kernel<<<1, 64, 0, stream>>>(img_loss, Bn, (float*)d_out);
}